// Round 7
// baseline (635.955 us; speedup 1.0000x reference)
//
#include <hip/hip_runtime.h>
#include <cmath>

// Problem constants
#define NB   128      // batch
#define NT   64       // time
#define NV   16000    // vocab
#define NVP  16384    // vocab padded to 64 col-tiles of 256 (8 per XCD)
#define NE   128      // emb dim
#define NC   256      // context dim
#define NH   512      // hidden
#define G4   2048     // 4*NH
#define ECK  384      // NE+NC
#define BT   8192     // NB*NT

typedef __attribute__((ext_vector_type(8))) short bf16x8;
typedef __attribute__((ext_vector_type(4))) float f32x4;
typedef const void __attribute__((address_space(1)))* gptr_t;
typedef void __attribute__((address_space(3)))* sptr_t;

static __device__ __forceinline__ unsigned short f2bf(float f) {
    union { float f; unsigned u; } a; a.f = f;
    unsigned r = (a.u + 0x7fff + ((a.u >> 16) & 1)) >> 16;   // RNE
    return (unsigned short)r;
}

// ---------------------------------------------------------------------------
// K0: build inp_bf[t*128+b][384] = bf16(concat(emb_table[x[b][t]], context[b]))
// ---------------------------------------------------------------------------
__global__ void build_inp_bf(const int* __restrict__ x, const float* __restrict__ ctx,
                             const float* __restrict__ emb, unsigned short* __restrict__ inp) {
    int f = blockIdx.x * blockDim.x + threadIdx.x;   // float4 index
    const int total = BT * (ECK / 4);
    if (f >= total) return;
    int row = f / (ECK / 4);
    int c4  = f % (ECK / 4);
    int b = row & (NB - 1);
    int c = c4 * 4;
    float4 v;
    if (c < NE) {
        int t = row >> 7;
        int tok = x[b * NT + t];
        v = *(const float4*)(emb + tok * NE + c);
    } else {
        v = *(const float4*)(ctx + b * NC + (c - NE));
    }
    ushort4 o;
    o.x = f2bf(v.x); o.y = f2bf(v.y); o.z = f2bf(v.z); o.w = f2bf(v.w);
    ((ushort4*)inp)[f] = o;
}

// ---------------------------------------------------------------------------
// K0b: fp32 -> bf16 convert (W_dec, W_hh, W_ih)
// ---------------------------------------------------------------------------
__global__ void f32_to_bf16(const float* __restrict__ src, unsigned short* __restrict__ dst, int n4) {
    int i = blockIdx.x * blockDim.x + threadIdx.x;
    if (i >= n4) return;
    float4 v = ((const float4*)src)[i];
    ushort4 o;
    o.x = f2bf(v.x); o.y = f2bf(v.y); o.z = f2bf(v.z); o.w = f2bf(v.w);
    ((ushort4*)dst)[i] = o;
}

// ---------------------------------------------------------------------------
// K0c: padded decoder bias: bdp[v] = v<NV ? b_dec[v] : -100  (exp(-100)=0)
// ---------------------------------------------------------------------------
__global__ void pad_bdec(const float* __restrict__ b_dec, float* __restrict__ bdp) {
    int i = blockIdx.x * blockDim.x + threadIdx.x;
    if (i >= NVP) return;
    bdp[i] = (i < NV) ? b_dec[i] : -100.f;
}

// ---------------------------------------------------------------------------
// K1: xg = inp_bf @ W_ih^T + b_ih + b_hh  (bf16 MFMA, m97 structure, K=384)
// ---------------------------------------------------------------------------
__global__ __launch_bounds__(256, 2) void gemm_xg_bf(
    const unsigned short* __restrict__ A,   // inp_bf [BT][384]
    const unsigned short* __restrict__ Bw,  // wih_bf [2048][384]
    const float* __restrict__ b_ih, const float* __restrict__ b_hh,
    float* __restrict__ xg)                 // [BT][2048] f32
{
    __shared__ short As[128 * 64];
    __shared__ short Bs[128 * 64];
    const int tid  = threadIdx.x;
    const int lane = tid & 63;
    const int wv   = tid >> 6;
    const int wr   = wv >> 1, wc = wv & 1;
    const int rowBase = blockIdx.y * 128;
    const int colBase = blockIdx.x * 128;

    f32x4 acc[4][4];
#pragma unroll
    for (int m = 0; m < 4; m++)
#pragma unroll
        for (int n = 0; n < 4; n++) acc[m][n] = (f32x4){0.f, 0.f, 0.f, 0.f};

    for (int kb = 0; kb < ECK; kb += 64) {
#pragma unroll
        for (int i = 0; i < 4; ++i) {
            int f = tid + i * 256;
            int r = f >> 3, pc = f & 7;
            int lc = pc ^ (r & 7);
            const unsigned short* srcA = A  + (size_t)(rowBase + r) * ECK + kb + lc * 8;
            const unsigned short* srcB = Bw + (size_t)(colBase + r) * ECK + kb + lc * 8;
            __builtin_amdgcn_global_load_lds((gptr_t)srcA, (sptr_t)(As + f * 8), 16, 0, 0);
            __builtin_amdgcn_global_load_lds((gptr_t)srcB, (sptr_t)(Bs + f * 8), 16, 0, 0);
        }
        __syncthreads();
#pragma unroll
        for (int kk = 0; kk < 2; ++kk) {
            bf16x8 af[4], bfr[4];
#pragma unroll
            for (int m = 0; m < 4; ++m) {
                int r  = wr * 64 + m * 16 + (lane & 15);
                int pc = (kk * 4 + (lane >> 4)) ^ (r & 7);
                af[m] = *(const bf16x8*)(As + r * 64 + pc * 8);
            }
#pragma unroll
            for (int n = 0; n < 4; ++n) {
                int r  = wc * 64 + n * 16 + (lane & 15);
                int pc = (kk * 4 + (lane >> 4)) ^ (r & 7);
                bfr[n] = *(const bf16x8*)(Bs + r * 64 + pc * 8);
            }
#pragma unroll
            for (int m = 0; m < 4; ++m)
#pragma unroll
                for (int n = 0; n < 4; ++n)
                    acc[m][n] = __builtin_amdgcn_mfma_f32_16x16x32_bf16(af[m], bfr[n], acc[m][n], 0, 0, 0);
        }
        __syncthreads();
    }
    const int rBase = rowBase + wr * 64;
    const int cBase = colBase + wc * 64;
#pragma unroll
    for (int n = 0; n < 4; ++n) {
        int col = cBase + n * 16 + (lane & 15);
        float bias = b_ih[col] + b_hh[col];
#pragma unroll
        for (int m = 0; m < 4; ++m)
#pragma unroll
            for (int reg = 0; reg < 4; ++reg) {
                int row = rBase + m * 16 + (lane >> 4) * 4 + reg;
                xg[(size_t)row * G4 + col] = acc[m][n][reg] + bias;
            }
    }
}

// ---------------------------------------------------------------------------
// K2: persistent LSTM — all 64 timesteps in one kernel. (unchanged from r5)
// ---------------------------------------------------------------------------
__global__ __launch_bounds__(256, 1) void lstm_persistent(
    const unsigned short* __restrict__ whh_bf,      // [2048][512] bf16
    const float* __restrict__ xg,                   // [BT][2048] f32, row t*128+b
    unsigned short* __restrict__ hx,                // [NT][128][512] bf16 (hx[0] zeroed)
    unsigned short* __restrict__ hs_bf,             // [8192][512] bf16, row b*64+t
    unsigned int* __restrict__ flags)               // [NT][8][32] zeroed
{
    __shared__ short Ws[64 * 512];      // 64 KB W_hh slice (rows c=g*16+j)
    __shared__ short As[16 * 512];      // 16 KB staged h panel (chunk-swizzled)
    __shared__ float Cs[16][68];        // C scratch (padded: 2-way max)
    __shared__ float cst[256];          // persistent c state
    __shared__ unsigned short hpk[256]; // h patch pack buffer [b*16+j]
    const int tid  = threadIdx.x;
    const int lane = tid & 63;
    const int wv   = tid >> 6;
    const int bid  = blockIdx.x;
    const int bb = bid & 7;             // batch group -> same XCD (heuristic)
    const int hb = bid >> 3;            // h-slice
    const int hBase = hb * 16;
    const int bBase = bb * 16;

    unsigned long long* hx64 = (unsigned long long*)hx;

    // stage W slice once; LDS slot ch of row r holds logical chunk ch^(r&7)
#pragma unroll
    for (int i = 0; i < 16; ++i) {
        int f = tid + i * 256;
        int r = f >> 6, ch = f & 63;
        int g = r >> 4, j = r & 15;
        const unsigned short* src = whh_bf + (size_t)((g << 9) + hBase + j) * NH + ((ch ^ (r & 7)) << 3);
        __builtin_amdgcn_global_load_lds((gptr_t)src, (sptr_t)(Ws + f * 8), 16, 0, 0);
    }
    cst[tid] = 0.f;
    __syncthreads();

    const int gb = tid >> 4, gj = tid & 15;          // gate-stage mapping
    const int hAbs = hBase + gj;

#pragma unroll 1
    for (int t = 0; t < NT; ++t) {
        // --- prefetch xg for this step (barrier-independent; hides HBM latency)
        const float* xgr = xg + (size_t)(t * NB + bBase + gb) * G4 + hAbs;
        float x0 = xgr[0];
        float x1 = xgr[NH];
        float x2 = xgr[2 * NH];
        float x3 = xgr[3 * NH];

        // --- wait for step t's h panel (written at end of step t-1)
        if (t > 0) {
            const unsigned int* fl = flags + (size_t)(t - 1) * 256 + bb * 32;
            unsigned int v;
            do {
                v = __hip_atomic_load(&fl[lane & 31], __ATOMIC_RELAXED,
                                      __HIP_MEMORY_SCOPE_AGENT);
            } while (!__all(v != 0));
        }

        // --- stage h panel: NORMAL cached global_load_lds (w=16), swizzled source
        const unsigned short* hsrc = hx + (size_t)t * NB * NH;
#pragma unroll
        for (int i = 0; i < 4; ++i) {
            int f = tid + i * 256;
            int r = f >> 6, ch = f & 63;
            const unsigned short* src = hsrc + (size_t)(bBase + r) * NH + ((ch ^ (r & 7)) << 3);
            __builtin_amdgcn_global_load_lds((gptr_t)src, (sptr_t)(As + f * 8), 16, 0, 0);
        }
        __syncthreads();

        // --- C[16][64] = h(16x512) @ Ws(64x512)^T ; wave wv owns n-tile wv
        f32x4 acc = (f32x4){0.f, 0.f, 0.f, 0.f};
        const int ar = lane & 15;
        const int br = wv * 16 + (lane & 15);
#pragma unroll
        for (int kc = 0; kc < 16; ++kc) {
            int cA = (kc * 4 + (lane >> 4)) ^ (ar & 7);
            int cB = (kc * 4 + (lane >> 4)) ^ (br & 7);
            bf16x8 a = *(const bf16x8*)(As + ar * 512 + cA * 8);
            bf16x8 b = *(const bf16x8*)(Ws + br * 512 + cB * 8);
            acc = __builtin_amdgcn_mfma_f32_16x16x32_bf16(a, b, acc, 0, 0, 0);
        }
#pragma unroll
        for (int reg = 0; reg < 4; ++reg)
            Cs[(lane >> 4) * 4 + reg][wv * 16 + (lane & 15)] = acc[reg];
        __syncthreads();

        // --- gates (thread -> b=gb, j=gj) using prefetched xg
        {
            float gi = Cs[gb][gj]      + x0;
            float gf = Cs[gb][16 + gj] + x1;
            float gg = Cs[gb][32 + gj] + x2;
            float go = Cs[gb][48 + gj] + x3;
            float i_ = 1.f / (1.f + __expf(-gi));
            float f_ = 1.f / (1.f + __expf(-gf));
            float o_ = 1.f / (1.f + __expf(-go));
            float cp = cst[tid];
            float cn = f_ * cp + i_ * tanhf(gg);
            float hn = o_ * tanhf(cn);
            cst[tid] = cn;
            unsigned short h16 = f2bf(hn);
            hs_bf[((size_t)(bBase + gb) * NT + t) * NH + hAbs] = h16;  // normal store
            hpk[tid] = h16;
        }
        __syncthreads();

        // --- publish h patch -> hx[t+1] (agent atomics, write-through to IC),
        //     then per-producer flag (plain agent store, NO RMW)
        if (t < NT - 1) {
            if (wv == 0) {
                int b = lane >> 2, q = lane & 3;
                unsigned long long v = *(const unsigned long long*)&hpk[b * 16 + q * 4];
                __hip_atomic_store(
                    &hx64[(size_t)(t + 1) * NB * (NH / 4)
                          + (size_t)(bBase + b) * (NH / 4) + (hBase >> 2) + q],
                    v, __ATOMIC_RELAXED, __HIP_MEMORY_SCOPE_AGENT);
                asm volatile("s_waitcnt vmcnt(0)" ::: "memory");   // complete at IC
                if (lane == 0)
                    __hip_atomic_store(&flags[(size_t)t * 256 + bb * 32 + hb], 1u,
                                       __ATOMIC_RELAXED, __HIP_MEMORY_SCOPE_AGENT);
            }
            __syncthreads();   // hpk stable until wave0 consumed it
        }
    }
}

// ---------------------------------------------------------------------------
// K3: decoder GEMM (bf16 MFMA) + fused log-sum-exp.
// 256x256 tile, BK=64, 8 waves (2Mx4N), 512 thr, 128KB LDS double-buffer.
// Counted-vmcnt pipeline (T3/T4): STAGE(next) -> vmcnt(8) -> s_barrier ->
// setprio(1) 64 MFMA setprio(0) -> s_barrier. Never drains vmcnt to 0 in loop.
// XCD stripe: col-tile = (bid&7)*8 + ((bid>>3)&7) -> 2MB B per XCD L2.
// ---------------------------------------------------------------------------
__global__ __launch_bounds__(512, 2) void decoder_mfma(
    const unsigned short* __restrict__ A,   // hs_bf [BT][512]
    const unsigned short* __restrict__ Bw,  // W_dec_bf [NVP][512]
    const float* __restrict__ b_dec,        // padded [NVP]
    const int* __restrict__ y,
    float* __restrict__ sumexp,
    float* __restrict__ picked)
{
    __shared__ short Lds[2 * 32768];        // [buf][A(16384) | B(16384)]
    const int tid  = threadIdx.x;
    const int lane = tid & 63;
    const int wv   = tid >> 6;              // 8 waves
    const int wr   = wv >> 2, wc = wv & 3;  // 2x4 wave grid; wave out = 128x64
    const int bid  = blockIdx.x;
    const int xcd  = bid & 7;
    const int idx  = bid >> 3;
    const int rowBase = (idx >> 3) * 256;
    const int colBase = (xcd * 8 + (idx & 7)) * 256;

    f32x4 acc[8][4];
#pragma unroll
    for (int m = 0; m < 8; m++)
#pragma unroll
        for (int n = 0; n < 4; n++) acc[m][n] = (f32x4){0.f, 0.f, 0.f, 0.f};

    // stage K-tile kt (64 wide) into buffer buf: 4 A-loads + 4 B-loads / thread
#define DSTAGE(buf, kt)                                                              \
    {                                                                                \
        short* As_ = Lds + (buf) * 32768;                                            \
        short* Bs_ = As_ + 16384;                                                    \
        int kb_ = (kt) * 64;                                                         \
        _Pragma("unroll")                                                            \
        for (int i = 0; i < 4; ++i) {                                                \
            int f = tid + i * 512;                                                   \
            int r = f >> 3, pc = f & 7;                                              \
            int lc = pc ^ (r & 7);                                                   \
            __builtin_amdgcn_global_load_lds(                                        \
                (gptr_t)(A + (size_t)(rowBase + r) * NH + kb_ + lc * 8),             \
                (sptr_t)(As_ + f * 8), 16, 0, 0);                                    \
        }                                                                            \
        _Pragma("unroll")                                                            \
        for (int i = 0; i < 4; ++i) {                                                \
            int f = tid + i * 512;                                                   \
            int r = f >> 3, pc = f & 7;                                              \
            int lc = pc ^ (r & 7);                                                   \
            __builtin_amdgcn_global_load_lds(                                        \
                (gptr_t)(Bw + (size_t)(colBase + r) * NH + kb_ + lc * 8),            \
                (sptr_t)(Bs_ + f * 8), 16, 0, 0);                                    \
        }                                                                            \
    }

    DSTAGE(0, 0);
#pragma unroll 1
    for (int kt = 0; kt < 8; ++kt) {
        const int cur = kt & 1;
        if (kt < 7) {
            DSTAGE(cur ^ 1, kt + 1);
            asm volatile("s_waitcnt vmcnt(8)" ::: "memory");   // buf[cur] complete
        } else {
            asm volatile("s_waitcnt vmcnt(0)" ::: "memory");
        }
        asm volatile("s_barrier" ::: "memory");                // all waves' loads done
        const short* As_ = Lds + cur * 32768;
        const short* Bs_ = As_ + 16384;
        __builtin_amdgcn_s_setprio(1);
#pragma unroll
        for (int kk = 0; kk < 2; ++kk) {
            bf16x8 af[8], bfr[4];
#pragma unroll
            for (int m = 0; m < 8; ++m) {
                int r  = wr * 128 + m * 16 + (lane & 15);
                int pc = (kk * 4 + (lane >> 4)) ^ (r & 7);
                af[m] = *(const bf16x8*)(As_ + r * 64 + pc * 8);
            }
#pragma unroll
            for (int n = 0; n < 4; ++n) {
                int r  = wc * 64 + n * 16 + (lane & 15);
                int pc = (kk * 4 + (lane >> 4)) ^ (r & 7);
                bfr[n] = *(const bf16x8*)(Bs_ + r * 64 + pc * 8);
            }
#pragma unroll
            for (int m = 0; m < 8; ++m)
#pragma unroll
                for (int n = 0; n < 4; ++n)
                    acc[m][n] = __builtin_amdgcn_mfma_f32_16x16x32_bf16(af[m], bfr[n], acc[m][n], 0, 0, 0);
        }
        __builtin_amdgcn_s_setprio(0);
        asm volatile("s_barrier" ::: "memory");                // reads done before overwrite
    }
#undef DSTAGE

    // Epilogue: wave out rows rBase..+127 (m,reg), cols cBase..+63 (n).
    const int rBase = rowBase + wr * 128;
    const int cBase = colBase + wc * 64;
    int yv[8][4];
#pragma unroll
    for (int m = 0; m < 8; ++m)
#pragma unroll
        for (int reg = 0; reg < 4; ++reg)
            yv[m][reg] = y[rBase + m * 16 + (lane >> 4) * 4 + reg];

    float rs[8][4];
#pragma unroll
    for (int m = 0; m < 8; ++m)
#pragma unroll
        for (int reg = 0; reg < 4; ++reg) rs[m][reg] = 0.f;

#pragma unroll
    for (int n = 0; n < 4; ++n) {
        int v = cBase + n * 16 + (lane & 15);
        float bd = b_dec[v];
#pragma unroll
        for (int m = 0; m < 8; ++m)
#pragma unroll
            for (int reg = 0; reg < 4; ++reg) {
                float logit = acc[m][n][reg] + bd;
                if (v == yv[m][reg])
                    picked[rBase + m * 16 + (lane >> 4) * 4 + reg] = logit;
                rs[m][reg] += __expf(logit);
            }
    }
#pragma unroll
    for (int m = 0; m < 8; ++m)
#pragma unroll
        for (int reg = 0; reg < 4; ++reg) {
            float s = rs[m][reg];
            s += __shfl_xor(s, 1);
            s += __shfl_xor(s, 2);
            s += __shfl_xor(s, 4);
            s += __shfl_xor(s, 8);
            if ((lane & 15) == 0)
                atomicAdd(&sumexp[rBase + m * 16 + (lane >> 4) * 4 + reg], s);
        }
}

// ---------------------------------------------------------------------------
// K4: loss[b] = -sum_t (picked[b*T+t] - log(sumexp[b*T+t]))
// ---------------------------------------------------------------------------
__global__ void loss_kernel(const float* __restrict__ picked,
                            const float* __restrict__ sumexp,
                            float* __restrict__ out) {
    int b = threadIdx.x;
    if (b >= NB) return;
    float s = 0.f;
    for (int t = 0; t < NT; t++) {
        int r = b * NT + t;
        s += picked[r] - logf(sumexp[r]);
    }
    out[b] = -s;
}

// ---------------------------------------------------------------------------
extern "C" void kernel_launch(void* const* d_in, const int* in_sizes, int n_in,
                              void* d_out, int out_size, void* d_ws, size_t ws_size,
                              hipStream_t stream) {
    const int*   x     = (const int*)d_in[0];
    const int*   y     = (const int*)d_in[1];
    const float* ctx   = (const float*)d_in[2];
    const float* emb   = (const float*)d_in[3];
    const float* W_ih  = (const float*)d_in[4];
    const float* W_hh  = (const float*)d_in[5];
    const float* b_ih  = (const float*)d_in[6];
    const float* b_hh  = (const float*)d_in[7];
    const float* W_dec = (const float*)d_in[8];
    const float* b_dec = (const float*)d_in[9];
    float* out = (float*)d_out;

    // workspace carve
    float*          ws      = (float*)d_ws;
    float*          xg      = ws;                               // 8192*2048 f32 (64 MB)
    float*          sumexp  = xg + (size_t)BT * G4;             // 8192 f32
    float*          picked  = sumexp + BT;                      // 8192 f32
    float*          bdp     = picked + BT;                      // 16384 f32 padded bias
    unsigned short* inp_bf  = (unsigned short*)(bdp + NVP);     // 8192*384  bf16
    unsigned short* hs_bf   = inp_bf + (size_t)BT * ECK;        // 8192*512  bf16
    unsigned short* wdec_bf = hs_bf + (size_t)BT * NH;          // 16384*512 bf16 (padded)
    unsigned short* whh_bf  = wdec_bf + (size_t)NVP * NH;       // 2048*512  bf16
    unsigned short* wih_bf  = whh_bf + (size_t)G4 * NH;         // 2048*384  bf16
    unsigned short* hx      = wih_bf + (size_t)G4 * ECK;        // 64*128*512 bf16 (8 MB)
    unsigned int*   flags   = (unsigned int*)(hx + (size_t)NT * NB * NH);  // 64*8*32 u32

    hipMemsetAsync(hx, 0, NB * NH * sizeof(unsigned short), stream);       // hx[0] = h0 = 0
    hipMemsetAsync(flags, 0, (size_t)NT * 256 * sizeof(unsigned int), stream);
    hipMemsetAsync(sumexp, 0, BT * sizeof(float), stream);
    // zero W_dec pad rows (16000..16383)
    hipMemsetAsync(wdec_bf + (size_t)NV * NH, 0, (size_t)(NVP - NV) * NH * sizeof(unsigned short), stream);

    pad_bdec<<<(NVP + 255) / 256, 256, 0, stream>>>(b_dec, bdp);

    f32_to_bf16<<<(NV * NH / 4 + 255) / 256, 256, 0, stream>>>(W_dec, wdec_bf, NV * NH / 4);
    f32_to_bf16<<<(G4 * NH / 4 + 255) / 256, 256, 0, stream>>>(W_hh, whh_bf, G4 * NH / 4);
    f32_to_bf16<<<(G4 * ECK / 4 + 255) / 256, 256, 0, stream>>>(W_ih, wih_bf, G4 * ECK / 4);

    build_inp_bf<<<(BT * (ECK / 4) + 255) / 256, 256, 0, stream>>>(x, ctx, emb, inp_bf);

    gemm_xg_bf<<<dim3(G4 / 128, BT / 128), 256, 0, stream>>>(inp_bf, wih_bf, b_ih, b_hh, xg);

    lstm_persistent<<<256, 256, 0, stream>>>(whh_bf, xg, hx, hs_bf, flags);

    decoder_mfma<<<(NVP / 256) * (BT / 256), 512, 0, stream>>>(
        hs_bf, wdec_bf, bdp, y, sumexp, picked);

    loss_kernel<<<1, 128, 0, stream>>>(picked, sumexp, out);
}

// Round 8
// 539.781 us; speedup vs baseline: 1.1782x; 1.1782x over previous
//
#include <hip/hip_runtime.h>
#include <cmath>

// Problem constants
#define NB   128      // batch
#define NT   64       // time
#define NV   16000    // vocab
#define NVP  16384    // vocab padded to 128 col-tiles (16 per XCD)
#define NE   128      // emb dim
#define NC   256      // context dim
#define NH   512      // hidden
#define G4   2048     // 4*NH
#define ECK  384      // NE+NC
#define BT   8192     // NB*NT

typedef __attribute__((ext_vector_type(8))) short bf16x8;
typedef __attribute__((ext_vector_type(4))) float f32x4;
typedef const void __attribute__((address_space(1)))* gptr_t;
typedef void __attribute__((address_space(3)))* sptr_t;

static __device__ __forceinline__ unsigned short f2bf(float f) {
    union { float f; unsigned u; } a; a.f = f;
    unsigned r = (a.u + 0x7fff + ((a.u >> 16) & 1)) >> 16;   // RNE
    return (unsigned short)r;
}

// ---------------------------------------------------------------------------
// K0: build inp_bf[t*128+b][384] = bf16(concat(emb_table[x[b][t]], context[b]))
// ---------------------------------------------------------------------------
__global__ void build_inp_bf(const int* __restrict__ x, const float* __restrict__ ctx,
                             const float* __restrict__ emb, unsigned short* __restrict__ inp) {
    int f = blockIdx.x * blockDim.x + threadIdx.x;   // float4 index
    const int total = BT * (ECK / 4);
    if (f >= total) return;
    int row = f / (ECK / 4);
    int c4  = f % (ECK / 4);
    int b = row & (NB - 1);
    int c = c4 * 4;
    float4 v;
    if (c < NE) {
        int t = row >> 7;
        int tok = x[b * NT + t];
        v = *(const float4*)(emb + tok * NE + c);
    } else {
        v = *(const float4*)(ctx + b * NC + (c - NE));
    }
    ushort4 o;
    o.x = f2bf(v.x); o.y = f2bf(v.y); o.z = f2bf(v.z); o.w = f2bf(v.w);
    ((ushort4*)inp)[f] = o;
}

// ---------------------------------------------------------------------------
// K0b: fp32 -> bf16 convert (W_dec, W_hh, W_ih)
// ---------------------------------------------------------------------------
__global__ void f32_to_bf16(const float* __restrict__ src, unsigned short* __restrict__ dst, int n4) {
    int i = blockIdx.x * blockDim.x + threadIdx.x;
    if (i >= n4) return;
    float4 v = ((const float4*)src)[i];
    ushort4 o;
    o.x = f2bf(v.x); o.y = f2bf(v.y); o.z = f2bf(v.z); o.w = f2bf(v.w);
    ((ushort4*)dst)[i] = o;
}

// ---------------------------------------------------------------------------
// K0c: padded decoder bias: bdp[v] = v<NV ? b_dec[v] : -100  (exp(-100)=0)
// ---------------------------------------------------------------------------
__global__ void pad_bdec(const float* __restrict__ b_dec, float* __restrict__ bdp) {
    int i = blockIdx.x * blockDim.x + threadIdx.x;
    if (i >= NVP) return;
    bdp[i] = (i < NV) ? b_dec[i] : -100.f;
}

// ---------------------------------------------------------------------------
// K1: xg = inp_bf @ W_ih^T + b_ih + b_hh  (bf16 MFMA, m97 structure, K=384)
// ---------------------------------------------------------------------------
__global__ __launch_bounds__(256, 2) void gemm_xg_bf(
    const unsigned short* __restrict__ A,   // inp_bf [BT][384]
    const unsigned short* __restrict__ Bw,  // wih_bf [2048][384]
    const float* __restrict__ b_ih, const float* __restrict__ b_hh,
    float* __restrict__ xg)                 // [BT][2048] f32
{
    __shared__ short As[128 * 64];
    __shared__ short Bs[128 * 64];
    const int tid  = threadIdx.x;
    const int lane = tid & 63;
    const int wv   = tid >> 6;
    const int wr   = wv >> 1, wc = wv & 1;
    const int rowBase = blockIdx.y * 128;
    const int colBase = blockIdx.x * 128;

    f32x4 acc[4][4];
#pragma unroll
    for (int m = 0; m < 4; m++)
#pragma unroll
        for (int n = 0; n < 4; n++) acc[m][n] = (f32x4){0.f, 0.f, 0.f, 0.f};

    for (int kb = 0; kb < ECK; kb += 64) {
#pragma unroll
        for (int i = 0; i < 4; ++i) {
            int f = tid + i * 256;
            int r = f >> 3, pc = f & 7;
            int lc = pc ^ (r & 7);
            const unsigned short* srcA = A  + (size_t)(rowBase + r) * ECK + kb + lc * 8;
            const unsigned short* srcB = Bw + (size_t)(colBase + r) * ECK + kb + lc * 8;
            __builtin_amdgcn_global_load_lds((gptr_t)srcA, (sptr_t)(As + f * 8), 16, 0, 0);
            __builtin_amdgcn_global_load_lds((gptr_t)srcB, (sptr_t)(Bs + f * 8), 16, 0, 0);
        }
        __syncthreads();
#pragma unroll
        for (int kk = 0; kk < 2; ++kk) {
            bf16x8 af[4], bfr[4];
#pragma unroll
            for (int m = 0; m < 4; ++m) {
                int r  = wr * 64 + m * 16 + (lane & 15);
                int pc = (kk * 4 + (lane >> 4)) ^ (r & 7);
                af[m] = *(const bf16x8*)(As + r * 64 + pc * 8);
            }
#pragma unroll
            for (int n = 0; n < 4; ++n) {
                int r  = wc * 64 + n * 16 + (lane & 15);
                int pc = (kk * 4 + (lane >> 4)) ^ (r & 7);
                bfr[n] = *(const bf16x8*)(Bs + r * 64 + pc * 8);
            }
#pragma unroll
            for (int m = 0; m < 4; ++m)
#pragma unroll
                for (int n = 0; n < 4; ++n)
                    acc[m][n] = __builtin_amdgcn_mfma_f32_16x16x32_bf16(af[m], bfr[n], acc[m][n], 0, 0, 0);
        }
        __syncthreads();
    }
    const int rBase = rowBase + wr * 64;
    const int cBase = colBase + wc * 64;
#pragma unroll
    for (int n = 0; n < 4; ++n) {
        int col = cBase + n * 16 + (lane & 15);
        float bias = b_ih[col] + b_hh[col];
#pragma unroll
        for (int m = 0; m < 4; ++m)
#pragma unroll
            for (int reg = 0; reg < 4; ++reg) {
                int row = rBase + m * 16 + (lane >> 4) * 4 + reg;
                xg[(size_t)row * G4 + col] = acc[m][n][reg] + bias;
            }
    }
}

// ---------------------------------------------------------------------------
// K2: persistent LSTM — all 64 timesteps in one kernel.
// 1-D grid 256 blocks: bb = bid&7 (batch group, XCD co-location heuristic),
// hb = bid>>3 (h-slice). Producer publishes h via agent-atomic u64 stores
// (write-through to IC), sets a PER-PRODUCER flag (plain store, no RMW).
// Round-7 change: ONLY WAVE 0 polls the 32 flags (was all 4 waves -> 4x
// redundant same-address IC atomic-load traffic from 256 blocks), then
// __syncthreads releases the block.
// ---------------------------------------------------------------------------
__global__ __launch_bounds__(256, 1) void lstm_persistent(
    const unsigned short* __restrict__ whh_bf,      // [2048][512] bf16
    const float* __restrict__ xg,                   // [BT][2048] f32, row t*128+b
    unsigned short* __restrict__ hx,                // [NT][128][512] bf16 (hx[0] zeroed)
    unsigned short* __restrict__ hs_bf,             // [8192][512] bf16, row b*64+t
    unsigned int* __restrict__ flags)               // [NT][8][32] zeroed
{
    __shared__ short Ws[64 * 512];      // 64 KB W_hh slice (rows c=g*16+j)
    __shared__ short As[16 * 512];      // 16 KB staged h panel (chunk-swizzled)
    __shared__ float Cs[16][68];        // C scratch (padded: 2-way max)
    __shared__ float cst[256];          // persistent c state
    __shared__ unsigned short hpk[256]; // h patch pack buffer [b*16+j]
    const int tid  = threadIdx.x;
    const int lane = tid & 63;
    const int wv   = tid >> 6;
    const int bid  = blockIdx.x;
    const int bb = bid & 7;             // batch group -> same XCD (heuristic)
    const int hb = bid >> 3;            // h-slice
    const int hBase = hb * 16;
    const int bBase = bb * 16;

    unsigned long long* hx64 = (unsigned long long*)hx;

    // stage W slice once; LDS slot ch of row r holds logical chunk ch^(r&7)
#pragma unroll
    for (int i = 0; i < 16; ++i) {
        int f = tid + i * 256;
        int r = f >> 6, ch = f & 63;
        int g = r >> 4, j = r & 15;
        const unsigned short* src = whh_bf + (size_t)((g << 9) + hBase + j) * NH + ((ch ^ (r & 7)) << 3);
        __builtin_amdgcn_global_load_lds((gptr_t)src, (sptr_t)(Ws + f * 8), 16, 0, 0);
    }
    cst[tid] = 0.f;
    __syncthreads();

    const int gb = tid >> 4, gj = tid & 15;          // gate-stage mapping
    const int hAbs = hBase + gj;

#pragma unroll 1
    for (int t = 0; t < NT; ++t) {
        // --- prefetch xg for this step (barrier-independent; hides HBM latency)
        const float* xgr = xg + (size_t)(t * NB + bBase + gb) * G4 + hAbs;
        float x0 = xgr[0];
        float x1 = xgr[NH];
        float x2 = xgr[2 * NH];
        float x3 = xgr[3 * NH];

        // --- wait for step t's h panel (written at end of step t-1)
        //     wave 0 only: avoid 4x redundant same-address IC load streams
        if (t > 0) {
            if (wv == 0) {
                const unsigned int* fl = flags + (size_t)(t - 1) * 256 + bb * 32;
                unsigned int v;
                do {
                    v = __hip_atomic_load(&fl[lane & 31], __ATOMIC_RELAXED,
                                          __HIP_MEMORY_SCOPE_AGENT);
                } while (!__all(v != 0));
            }
            __syncthreads();
        }

        // --- stage h panel: NORMAL cached global_load_lds (w=16), swizzled source
        const unsigned short* hsrc = hx + (size_t)t * NB * NH;
#pragma unroll
        for (int i = 0; i < 4; ++i) {
            int f = tid + i * 256;
            int r = f >> 6, ch = f & 63;
            const unsigned short* src = hsrc + (size_t)(bBase + r) * NH + ((ch ^ (r & 7)) << 3);
            __builtin_amdgcn_global_load_lds((gptr_t)src, (sptr_t)(As + f * 8), 16, 0, 0);
        }
        __syncthreads();

        // --- C[16][64] = h(16x512) @ Ws(64x512)^T ; wave wv owns n-tile wv
        f32x4 acc = (f32x4){0.f, 0.f, 0.f, 0.f};
        const int ar = lane & 15;
        const int br = wv * 16 + (lane & 15);
#pragma unroll
        for (int kc = 0; kc < 16; ++kc) {
            int cA = (kc * 4 + (lane >> 4)) ^ (ar & 7);
            int cB = (kc * 4 + (lane >> 4)) ^ (br & 7);
            bf16x8 a = *(const bf16x8*)(As + ar * 512 + cA * 8);
            bf16x8 b = *(const bf16x8*)(Ws + br * 512 + cB * 8);
            acc = __builtin_amdgcn_mfma_f32_16x16x32_bf16(a, b, acc, 0, 0, 0);
        }
#pragma unroll
        for (int reg = 0; reg < 4; ++reg)
            Cs[(lane >> 4) * 4 + reg][wv * 16 + (lane & 15)] = acc[reg];
        __syncthreads();

        // --- gates (thread -> b=gb, j=gj) using prefetched xg
        {
            float gi = Cs[gb][gj]      + x0;
            float gf = Cs[gb][16 + gj] + x1;
            float gg = Cs[gb][32 + gj] + x2;
            float go = Cs[gb][48 + gj] + x3;
            float i_ = 1.f / (1.f + __expf(-gi));
            float f_ = 1.f / (1.f + __expf(-gf));
            float o_ = 1.f / (1.f + __expf(-go));
            float cp = cst[tid];
            float cn = f_ * cp + i_ * tanhf(gg);
            float hn = o_ * tanhf(cn);
            cst[tid] = cn;
            unsigned short h16 = f2bf(hn);
            hs_bf[((size_t)(bBase + gb) * NT + t) * NH + hAbs] = h16;  // normal store
            hpk[tid] = h16;
        }
        __syncthreads();

        // --- publish h patch -> hx[t+1] (agent atomics, write-through to IC),
        //     then per-producer flag (plain agent store, NO RMW)
        if (t < NT - 1) {
            if (wv == 0) {
                int b = lane >> 2, q = lane & 3;
                unsigned long long v = *(const unsigned long long*)&hpk[b * 16 + q * 4];
                __hip_atomic_store(
                    &hx64[(size_t)(t + 1) * NB * (NH / 4)
                          + (size_t)(bBase + b) * (NH / 4) + (hBase >> 2) + q],
                    v, __ATOMIC_RELAXED, __HIP_MEMORY_SCOPE_AGENT);
                asm volatile("s_waitcnt vmcnt(0)" ::: "memory");   // complete at IC
                if (lane == 0)
                    __hip_atomic_store(&flags[(size_t)t * 256 + bb * 32 + hb], 1u,
                                       __ATOMIC_RELAXED, __HIP_MEMORY_SCOPE_AGENT);
            }
            __syncthreads();   // hpk stable until wave0 consumed it
        }
    }
}

// ---------------------------------------------------------------------------
// K3: decoder GEMM (bf16 MFMA) + fused log-sum-exp.  (round-6 proven version)
// XCD-locality swizzle: 1-D grid 8192 blocks; hw maps bid->XCD round-robin
// (xcd = bid&7). idx = bid>>3: col = xcd*16 + (idx&15)  (16-col stripe per
// XCD -> B working set 2 MB, L2-resident), row = idx>>4 (16 consecutive
// blocks share one A panel). Vocab padded to 16384 (pad W rows=0, bias=-100).
// ---------------------------------------------------------------------------
__global__ __launch_bounds__(256, 2) void decoder_mfma(
    const unsigned short* __restrict__ A,   // hs_bf [BT][512]
    const unsigned short* __restrict__ Bw,  // W_dec_bf [NVP][512]
    const float* __restrict__ b_dec,        // padded [NVP]
    const int* __restrict__ y,
    float* __restrict__ sumexp,
    float* __restrict__ picked)
{
    __shared__ short As[128 * 64];
    __shared__ short Bs[128 * 64];
    const int tid  = threadIdx.x;
    const int lane = tid & 63;
    const int wv   = tid >> 6;
    const int wr   = wv >> 1, wc = wv & 1;
    const int bid  = blockIdx.x;
    const int xcd  = bid & 7;
    const int idx  = bid >> 3;
    const int rowBase = (idx >> 4) * 128;
    const int colBase = (xcd * 16 + (idx & 15)) * 128;

    f32x4 acc[4][4];
#pragma unroll
    for (int m = 0; m < 4; m++)
#pragma unroll
        for (int n = 0; n < 4; n++) acc[m][n] = (f32x4){0.f, 0.f, 0.f, 0.f};

    for (int kb = 0; kb < NH; kb += 64) {
#pragma unroll
        for (int i = 0; i < 4; ++i) {
            int f = tid + i * 256;
            int r = f >> 3, pc = f & 7;
            int lc = pc ^ (r & 7);
            const unsigned short* srcA = A  + (size_t)(rowBase + r) * NH + kb + lc * 8;
            const unsigned short* srcB = Bw + (size_t)(colBase + r) * NH + kb + lc * 8;
            __builtin_amdgcn_global_load_lds((gptr_t)srcA, (sptr_t)(As + f * 8), 16, 0, 0);
            __builtin_amdgcn_global_load_lds((gptr_t)srcB, (sptr_t)(Bs + f * 8), 16, 0, 0);
        }
        __syncthreads();
#pragma unroll
        for (int kk = 0; kk < 2; ++kk) {
            bf16x8 af[4], bfr[4];
#pragma unroll
            for (int m = 0; m < 4; ++m) {
                int r  = wr * 64 + m * 16 + (lane & 15);
                int pc = (kk * 4 + (lane >> 4)) ^ (r & 7);
                af[m] = *(const bf16x8*)(As + r * 64 + pc * 8);
            }
#pragma unroll
            for (int n = 0; n < 4; ++n) {
                int r  = wc * 64 + n * 16 + (lane & 15);
                int pc = (kk * 4 + (lane >> 4)) ^ (r & 7);
                bfr[n] = *(const bf16x8*)(Bs + r * 64 + pc * 8);
            }
#pragma unroll
            for (int m = 0; m < 4; ++m)
#pragma unroll
                for (int n = 0; n < 4; ++n)
                    acc[m][n] = __builtin_amdgcn_mfma_f32_16x16x32_bf16(af[m], bfr[n], acc[m][n], 0, 0, 0);
        }
        __syncthreads();
    }

    const int rBase = rowBase + wr * 64;
    const int cBase = colBase + wc * 64;
    int yv[4][4];
#pragma unroll
    for (int m = 0; m < 4; ++m)
#pragma unroll
        for (int reg = 0; reg < 4; ++reg)
            yv[m][reg] = y[rBase + m * 16 + (lane >> 4) * 4 + reg];

    float rs[4][4];
#pragma unroll
    for (int m = 0; m < 4; ++m)
#pragma unroll
        for (int reg = 0; reg < 4; ++reg) rs[m][reg] = 0.f;

#pragma unroll
    for (int n = 0; n < 4; ++n) {
        int v = cBase + n * 16 + (lane & 15);
        float bd = b_dec[v];
#pragma unroll
        for (int m = 0; m < 4; ++m)
#pragma unroll
            for (int reg = 0; reg < 4; ++reg) {
                float logit = acc[m][n][reg] + bd;
                if (v == yv[m][reg])
                    picked[rBase + m * 16 + (lane >> 4) * 4 + reg] = logit;
                rs[m][reg] += __expf(logit);
            }
    }
#pragma unroll
    for (int m = 0; m < 4; ++m)
#pragma unroll
        for (int reg = 0; reg < 4; ++reg) {
            float s = rs[m][reg];
            s += __shfl_xor(s, 1);
            s += __shfl_xor(s, 2);
            s += __shfl_xor(s, 4);
            s += __shfl_xor(s, 8);
            if ((lane & 15) == 0)
                atomicAdd(&sumexp[rBase + m * 16 + (lane >> 4) * 4 + reg], s);
        }
}

// ---------------------------------------------------------------------------
// K4: loss[b] = -sum_t (picked[b*T+t] - log(sumexp[b*T+t]))
// ---------------------------------------------------------------------------
__global__ void loss_kernel(const float* __restrict__ picked,
                            const float* __restrict__ sumexp,
                            float* __restrict__ out) {
    int b = threadIdx.x;
    if (b >= NB) return;
    float s = 0.f;
    for (int t = 0; t < NT; t++) {
        int r = b * NT + t;
        s += picked[r] - logf(sumexp[r]);
    }
    out[b] = -s;
}

// ---------------------------------------------------------------------------
extern "C" void kernel_launch(void* const* d_in, const int* in_sizes, int n_in,
                              void* d_out, int out_size, void* d_ws, size_t ws_size,
                              hipStream_t stream) {
    const int*   x     = (const int*)d_in[0];
    const int*   y     = (const int*)d_in[1];
    const float* ctx   = (const float*)d_in[2];
    const float* emb   = (const float*)d_in[3];
    const float* W_ih  = (const float*)d_in[4];
    const float* W_hh  = (const float*)d_in[5];
    const float* b_ih  = (const float*)d_in[6];
    const float* b_hh  = (const float*)d_in[7];
    const float* W_dec = (const float*)d_in[8];
    const float* b_dec = (const float*)d_in[9];
    float* out = (float*)d_out;

    // workspace carve
    float*          ws      = (float*)d_ws;
    float*          xg      = ws;                               // 8192*2048 f32 (64 MB)
    float*          sumexp  = xg + (size_t)BT * G4;             // 8192 f32
    float*          picked  = sumexp + BT;                      // 8192 f32
    float*          bdp     = picked + BT;                      // 16384 f32 padded bias
    unsigned short* inp_bf  = (unsigned short*)(bdp + NVP);     // 8192*384  bf16
    unsigned short* hs_bf   = inp_bf + (size_t)BT * ECK;        // 8192*512  bf16
    unsigned short* wdec_bf = hs_bf + (size_t)BT * NH;          // 16384*512 bf16 (padded)
    unsigned short* whh_bf  = wdec_bf + (size_t)NVP * NH;       // 2048*512  bf16
    unsigned short* wih_bf  = whh_bf + (size_t)G4 * NH;         // 2048*384  bf16
    unsigned short* hx      = wih_bf + (size_t)G4 * ECK;        // 64*128*512 bf16 (8 MB)
    unsigned int*   flags   = (unsigned int*)(hx + (size_t)NT * NB * NH);  // 64*8*32 u32

    hipMemsetAsync(hx, 0, NB * NH * sizeof(unsigned short), stream);       // hx[0] = h0 = 0
    hipMemsetAsync(flags, 0, (size_t)NT * 256 * sizeof(unsigned int), stream);
    hipMemsetAsync(sumexp, 0, BT * sizeof(float), stream);
    // zero W_dec pad rows (16000..16383)
    hipMemsetAsync(wdec_bf + (size_t)NV * NH, 0, (size_t)(NVP - NV) * NH * sizeof(unsigned short), stream);

    pad_bdec<<<(NVP + 255) / 256, 256, 0, stream>>>(b_dec, bdp);

    f32_to_bf16<<<(NV * NH / 4 + 255) / 256, 256, 0, stream>>>(W_dec, wdec_bf, NV * NH / 4);
    f32_to_bf16<<<(G4 * NH / 4 + 255) / 256, 256, 0, stream>>>(W_hh, whh_bf, G4 * NH / 4);
    f32_to_bf16<<<(G4 * ECK / 4 + 255) / 256, 256, 0, stream>>>(W_ih, wih_bf, G4 * ECK / 4);

    build_inp_bf<<<(BT * (ECK / 4) + 255) / 256, 256, 0, stream>>>(x, ctx, emb, inp_bf);

    gemm_xg_bf<<<dim3(G4 / 128, BT / 128), 256, 0, stream>>>(inp_bf, wih_bf, b_ih, b_hh, xg);

    lstm_persistent<<<256, 256, 0, stream>>>(whh_bf, xg, hx, hs_bf, flags);

    decoder_mfma<<<(NVP / 128) * (BT / 128), 256, 0, stream>>>(
        hs_bf, wdec_bf, bdp, y, sumexp, picked);

    loss_kernel<<<1, 128, 0, stream>>>(picked, sumexp, out);
}

// Round 9
// 510.059 us; speedup vs baseline: 1.2468x; 1.0583x over previous
//
#include <hip/hip_runtime.h>
#include <cmath>

// Problem constants
#define NB   128      // batch
#define NT   64       // time
#define NV   16000    // vocab
#define NVP  16384    // vocab padded to 128 col-tiles (16 per XCD)
#define NE   128      // emb dim
#define NC   256      // context dim
#define NH   512      // hidden
#define G4   2048     // 4*NH
#define ECK  384      // NE+NC
#define BT   8192     // NB*NT

typedef __attribute__((ext_vector_type(8))) short bf16x8;
typedef __attribute__((ext_vector_type(4))) float f32x4;
typedef const void __attribute__((address_space(1)))* gptr_t;
typedef void __attribute__((address_space(3)))* sptr_t;

static __device__ __forceinline__ unsigned short f2bf(float f) {
    union { float f; unsigned u; } a; a.f = f;
    unsigned r = (a.u + 0x7fff + ((a.u >> 16) & 1)) >> 16;   // RNE
    return (unsigned short)r;
}

// ---------------------------------------------------------------------------
// K0: build inp_bf[t*128+b][384] = bf16(concat(emb_table[x[b][t]], context[b]))
// ---------------------------------------------------------------------------
__global__ void build_inp_bf(const int* __restrict__ x, const float* __restrict__ ctx,
                             const float* __restrict__ emb, unsigned short* __restrict__ inp) {
    int f = blockIdx.x * blockDim.x + threadIdx.x;   // float4 index
    const int total = BT * (ECK / 4);
    if (f >= total) return;
    int row = f / (ECK / 4);
    int c4  = f % (ECK / 4);
    int b = row & (NB - 1);
    int c = c4 * 4;
    float4 v;
    if (c < NE) {
        int t = row >> 7;
        int tok = x[b * NT + t];
        v = *(const float4*)(emb + tok * NE + c);
    } else {
        v = *(const float4*)(ctx + b * NC + (c - NE));
    }
    ushort4 o;
    o.x = f2bf(v.x); o.y = f2bf(v.y); o.z = f2bf(v.z); o.w = f2bf(v.w);
    ((ushort4*)inp)[f] = o;
}

// ---------------------------------------------------------------------------
// K0b: fp32 -> bf16 convert (W_dec, W_hh, W_ih)
// ---------------------------------------------------------------------------
__global__ void f32_to_bf16(const float* __restrict__ src, unsigned short* __restrict__ dst, int n4) {
    int i = blockIdx.x * blockDim.x + threadIdx.x;
    if (i >= n4) return;
    float4 v = ((const float4*)src)[i];
    ushort4 o;
    o.x = f2bf(v.x); o.y = f2bf(v.y); o.z = f2bf(v.z); o.w = f2bf(v.w);
    ((ushort4*)dst)[i] = o;
}

// ---------------------------------------------------------------------------
// K0c: padded decoder bias: bdp[v] = v<NV ? b_dec[v] : -100  (exp(-100)=0)
// ---------------------------------------------------------------------------
__global__ void pad_bdec(const float* __restrict__ b_dec, float* __restrict__ bdp) {
    int i = blockIdx.x * blockDim.x + threadIdx.x;
    if (i >= NVP) return;
    bdp[i] = (i < NV) ? b_dec[i] : -100.f;
}

// ---------------------------------------------------------------------------
// K2: persistent LSTM — all 64 timesteps, input-GEMM FUSED into the k-loop.
// 1-D grid 256 blocks: bb = bid&7, hb = bid>>3. Per step the block computes
// C[16b x 64gate] = h(16x512)@Whh_s^T + inp(16x384)@Wih_s^T in one MFMA
// accumulator (this IS the xg tile the old gemm_xg produced). W_ih slice
// staged once (48 KB); inp[t] panel (12 KB) staged at loop top so its L2
// latency hides under the flag-spin. Biases live in 4 registers.
// Cross-block h exchange: agent-atomic u64 publish -> per-producer flag ->
// wave0 polls 32 flags -> cached global_load_lds re-stage. (r5-r7 proven)
// LDS: 64+48+16+12+4.25+1.5 = ~146 KB -> 1 block/CU (as before).
// ---------------------------------------------------------------------------
__global__ __launch_bounds__(256, 1) void lstm_persistent(
    const unsigned short* __restrict__ whh_bf,      // [2048][512] bf16
    const unsigned short* __restrict__ wih_bf,      // [2048][384] bf16
    const unsigned short* __restrict__ inp_bf,      // [BT][384] bf16, row t*128+b
    const float* __restrict__ b_ih, const float* __restrict__ b_hh,
    unsigned short* __restrict__ hx,                // [NT][128][512] bf16 (hx[0] zeroed)
    unsigned short* __restrict__ hs_bf,             // [8192][512] bf16, row b*64+t
    unsigned int* __restrict__ flags)               // [NT][8][32] zeroed
{
    __shared__ short Ws[64 * 512];      // 64 KB W_hh slice (rows c=g*16+j)
    __shared__ short WI[64 * 384];      // 48 KB W_ih slice (same row map)
    __shared__ short As[16 * 512];      // 16 KB staged h panel (chunk-swizzled)
    __shared__ short Is[16 * 384];      // 12 KB staged inp panel (chunk-swizzled)
    __shared__ float Cs[16][68];        // C scratch (padded: 2-way max)
    __shared__ float cst[256];          // persistent c state
    __shared__ unsigned short hpk[256]; // h patch pack buffer [b*16+j]
    const int tid  = threadIdx.x;
    const int lane = tid & 63;
    const int wv   = tid >> 6;
    const int bid  = blockIdx.x;
    const int bb = bid & 7;             // batch group -> same XCD (heuristic)
    const int hb = bid >> 3;            // h-slice
    const int hBase = hb * 16;
    const int bBase = bb * 16;

    unsigned long long* hx64 = (unsigned long long*)hx;

    // stage W_hh slice once; LDS slot ch of row r holds logical chunk ch^(r&7)
#pragma unroll
    for (int i = 0; i < 16; ++i) {
        int f = tid + i * 256;
        int r = f >> 6, ch = f & 63;
        const unsigned short* src = whh_bf
            + (size_t)(((r >> 4) << 9) + hBase + (r & 15)) * NH + ((ch ^ (r & 7)) << 3);
        __builtin_amdgcn_global_load_lds((gptr_t)src, (sptr_t)(Ws + f * 8), 16, 0, 0);
    }
    // stage W_ih slice once (rows 64 x 48 chunks)
#pragma unroll
    for (int i = 0; i < 12; ++i) {
        int f = tid + i * 256;
        int r = f / 48, ch = f % 48;
        const unsigned short* src = wih_bf
            + (size_t)(((r >> 4) << 9) + hBase + (r & 15)) * ECK + ((ch ^ (r & 7)) << 3);
        __builtin_amdgcn_global_load_lds((gptr_t)src, (sptr_t)(WI + f * 8), 16, 0, 0);
    }
    cst[tid] = 0.f;
    __syncthreads();

    const int gb = tid >> 4, gj = tid & 15;          // gate-stage mapping
    const int hAbs = hBase + gj;
    const float bias0 = b_ih[hAbs]          + b_hh[hAbs];
    const float bias1 = b_ih[NH + hAbs]     + b_hh[NH + hAbs];
    const float bias2 = b_ih[2 * NH + hAbs] + b_hh[2 * NH + hAbs];
    const float bias3 = b_ih[3 * NH + hAbs] + b_hh[3 * NH + hAbs];

#pragma unroll 1
    for (int t = 0; t < NT; ++t) {
        // --- stage inp[t] panel (recurrence-independent: hides under the spin)
        const unsigned short* isrc = inp_bf + (size_t)(t * NB + bBase) * ECK;
#pragma unroll
        for (int i = 0; i < 3; ++i) {
            int f = tid + i * 256;           // 768 chunks: 16 rows x 48
            int r = f / 48, ch = f % 48;
            __builtin_amdgcn_global_load_lds(
                (gptr_t)(isrc + (size_t)r * ECK + ((ch ^ (r & 7)) << 3)),
                (sptr_t)(Is + f * 8), 16, 0, 0);
        }

        // --- wait for step t's h panel (written at end of step t-1); wave0 only
        if (t > 0) {
            if (wv == 0) {
                const unsigned int* fl = flags + (size_t)(t - 1) * 256 + bb * 32;
                unsigned int v;
                do {
                    v = __hip_atomic_load(&fl[lane & 31], __ATOMIC_RELAXED,
                                          __HIP_MEMORY_SCOPE_AGENT);
                } while (!__all(v != 0));
            }
            __syncthreads();
        }

        // --- stage h panel: NORMAL cached global_load_lds (w=16), swizzled source
        const unsigned short* hsrc = hx + (size_t)t * NB * NH;
#pragma unroll
        for (int i = 0; i < 4; ++i) {
            int f = tid + i * 256;
            int r = f >> 6, ch = f & 63;
            const unsigned short* src = hsrc + (size_t)(bBase + r) * NH + ((ch ^ (r & 7)) << 3);
            __builtin_amdgcn_global_load_lds((gptr_t)src, (sptr_t)(As + f * 8), 16, 0, 0);
        }
        __syncthreads();   // drains vmcnt: As + Is + (first iter) W slices ready

        // --- C[16][64] = h @ Ws^T (k=512) + inp @ WI^T (k=384); wave wv: n-tile wv
        f32x4 acc = (f32x4){0.f, 0.f, 0.f, 0.f};
        const int ar = lane & 15;
        const int br = wv * 16 + (lane & 15);
#pragma unroll
        for (int kc = 0; kc < 16; ++kc) {
            int cA = (kc * 4 + (lane >> 4)) ^ (ar & 7);
            int cB = (kc * 4 + (lane >> 4)) ^ (br & 7);
            bf16x8 a = *(const bf16x8*)(As + ar * 512 + cA * 8);
            bf16x8 b = *(const bf16x8*)(Ws + br * 512 + cB * 8);
            acc = __builtin_amdgcn_mfma_f32_16x16x32_bf16(a, b, acc, 0, 0, 0);
        }
#pragma unroll
        for (int kc = 0; kc < 12; ++kc) {
            int cA = (kc * 4 + (lane >> 4)) ^ (ar & 7);
            int cB = (kc * 4 + (lane >> 4)) ^ (br & 7);
            bf16x8 a = *(const bf16x8*)(Is + ar * ECK + cA * 8);
            bf16x8 b = *(const bf16x8*)(WI + br * ECK + cB * 8);
            acc = __builtin_amdgcn_mfma_f32_16x16x32_bf16(a, b, acc, 0, 0, 0);
        }
#pragma unroll
        for (int reg = 0; reg < 4; ++reg)
            Cs[(lane >> 4) * 4 + reg][wv * 16 + (lane & 15)] = acc[reg];
        __syncthreads();

        // --- gates (thread -> b=gb, j=gj); bias in registers
        {
            float gi = Cs[gb][gj]      + bias0;
            float gf = Cs[gb][16 + gj] + bias1;
            float gg = Cs[gb][32 + gj] + bias2;
            float go = Cs[gb][48 + gj] + bias3;
            float i_ = 1.f / (1.f + __expf(-gi));
            float f_ = 1.f / (1.f + __expf(-gf));
            float o_ = 1.f / (1.f + __expf(-go));
            float cp = cst[tid];
            float cn = f_ * cp + i_ * tanhf(gg);
            float hn = o_ * tanhf(cn);
            cst[tid] = cn;
            unsigned short h16 = f2bf(hn);
            hs_bf[((size_t)(bBase + gb) * NT + t) * NH + hAbs] = h16;  // normal store
            hpk[tid] = h16;
        }
        __syncthreads();

        // --- publish h patch -> hx[t+1] (agent atomics, write-through to IC),
        //     then per-producer flag (plain agent store, NO RMW)
        if (t < NT - 1) {
            if (wv == 0) {
                int b = lane >> 2, q = lane & 3;
                unsigned long long v = *(const unsigned long long*)&hpk[b * 16 + q * 4];
                __hip_atomic_store(
                    &hx64[(size_t)(t + 1) * NB * (NH / 4)
                          + (size_t)(bBase + b) * (NH / 4) + (hBase >> 2) + q],
                    v, __ATOMIC_RELAXED, __HIP_MEMORY_SCOPE_AGENT);
                asm volatile("s_waitcnt vmcnt(0)" ::: "memory");   // complete at IC
                if (lane == 0)
                    __hip_atomic_store(&flags[(size_t)t * 256 + bb * 32 + hb], 1u,
                                       __ATOMIC_RELAXED, __HIP_MEMORY_SCOPE_AGENT);
            }
            __syncthreads();   // hpk stable until wave0 consumed it
        }
    }
}

// ---------------------------------------------------------------------------
// K3: decoder GEMM (bf16 MFMA) + fused log-sum-exp.  (round-6 proven version)
// XCD-locality swizzle: 1-D grid 8192 blocks; col = (bid&7)*16 + (idx&15),
// row = idx>>4. B working set 2 MB per XCD L2. Vocab padded to 16384.
// ---------------------------------------------------------------------------
__global__ __launch_bounds__(256, 2) void decoder_mfma(
    const unsigned short* __restrict__ A,   // hs_bf [BT][512]
    const unsigned short* __restrict__ Bw,  // W_dec_bf [NVP][512]
    const float* __restrict__ b_dec,        // padded [NVP]
    const int* __restrict__ y,
    float* __restrict__ sumexp,
    float* __restrict__ picked)
{
    __shared__ short As[128 * 64];
    __shared__ short Bs[128 * 64];
    const int tid  = threadIdx.x;
    const int lane = tid & 63;
    const int wv   = tid >> 6;
    const int wr   = wv >> 1, wc = wv & 1;
    const int bid  = blockIdx.x;
    const int xcd  = bid & 7;
    const int idx  = bid >> 3;
    const int rowBase = (idx >> 4) * 128;
    const int colBase = (xcd * 16 + (idx & 15)) * 128;

    f32x4 acc[4][4];
#pragma unroll
    for (int m = 0; m < 4; m++)
#pragma unroll
        for (int n = 0; n < 4; n++) acc[m][n] = (f32x4){0.f, 0.f, 0.f, 0.f};

    for (int kb = 0; kb < NH; kb += 64) {
#pragma unroll
        for (int i = 0; i < 4; ++i) {
            int f = tid + i * 256;
            int r = f >> 3, pc = f & 7;
            int lc = pc ^ (r & 7);
            const unsigned short* srcA = A  + (size_t)(rowBase + r) * NH + kb + lc * 8;
            const unsigned short* srcB = Bw + (size_t)(colBase + r) * NH + kb + lc * 8;
            __builtin_amdgcn_global_load_lds((gptr_t)srcA, (sptr_t)(As + f * 8), 16, 0, 0);
            __builtin_amdgcn_global_load_lds((gptr_t)srcB, (sptr_t)(Bs + f * 8), 16, 0, 0);
        }
        __syncthreads();
#pragma unroll
        for (int kk = 0; kk < 2; ++kk) {
            bf16x8 af[4], bfr[4];
#pragma unroll
            for (int m = 0; m < 4; ++m) {
                int r  = wr * 64 + m * 16 + (lane & 15);
                int pc = (kk * 4 + (lane >> 4)) ^ (r & 7);
                af[m] = *(const bf16x8*)(As + r * 64 + pc * 8);
            }
#pragma unroll
            for (int n = 0; n < 4; ++n) {
                int r  = wc * 64 + n * 16 + (lane & 15);
                int pc = (kk * 4 + (lane >> 4)) ^ (r & 7);
                bfr[n] = *(const bf16x8*)(Bs + r * 64 + pc * 8);
            }
#pragma unroll
            for (int m = 0; m < 4; ++m)
#pragma unroll
                for (int n = 0; n < 4; ++n)
                    acc[m][n] = __builtin_amdgcn_mfma_f32_16x16x32_bf16(af[m], bfr[n], acc[m][n], 0, 0, 0);
        }
        __syncthreads();
    }

    const int rBase = rowBase + wr * 64;
    const int cBase = colBase + wc * 64;
    int yv[4][4];
#pragma unroll
    for (int m = 0; m < 4; ++m)
#pragma unroll
        for (int reg = 0; reg < 4; ++reg)
            yv[m][reg] = y[rBase + m * 16 + (lane >> 4) * 4 + reg];

    float rs[4][4];
#pragma unroll
    for (int m = 0; m < 4; ++m)
#pragma unroll
        for (int reg = 0; reg < 4; ++reg) rs[m][reg] = 0.f;

#pragma unroll
    for (int n = 0; n < 4; ++n) {
        int v = cBase + n * 16 + (lane & 15);
        float bd = b_dec[v];
#pragma unroll
        for (int m = 0; m < 4; ++m)
#pragma unroll
            for (int reg = 0; reg < 4; ++reg) {
                float logit = acc[m][n][reg] + bd;
                if (v == yv[m][reg])
                    picked[rBase + m * 16 + (lane >> 4) * 4 + reg] = logit;
                rs[m][reg] += __expf(logit);
            }
    }
#pragma unroll
    for (int m = 0; m < 4; ++m)
#pragma unroll
        for (int reg = 0; reg < 4; ++reg) {
            float s = rs[m][reg];
            s += __shfl_xor(s, 1);
            s += __shfl_xor(s, 2);
            s += __shfl_xor(s, 4);
            s += __shfl_xor(s, 8);
            if ((lane & 15) == 0)
                atomicAdd(&sumexp[rBase + m * 16 + (lane >> 4) * 4 + reg], s);
        }
}

// ---------------------------------------------------------------------------
// K4: loss[b] = -sum_t (picked[b*T+t] - log(sumexp[b*T+t]))
// ---------------------------------------------------------------------------
__global__ void loss_kernel(const float* __restrict__ picked,
                            const float* __restrict__ sumexp,
                            float* __restrict__ out) {
    int b = threadIdx.x;
    if (b >= NB) return;
    float s = 0.f;
    for (int t = 0; t < NT; t++) {
        int r = b * NT + t;
        s += picked[r] - logf(sumexp[r]);
    }
    out[b] = -s;
}

// ---------------------------------------------------------------------------
extern "C" void kernel_launch(void* const* d_in, const int* in_sizes, int n_in,
                              void* d_out, int out_size, void* d_ws, size_t ws_size,
                              hipStream_t stream) {
    const int*   x     = (const int*)d_in[0];
    const int*   y     = (const int*)d_in[1];
    const float* ctx   = (const float*)d_in[2];
    const float* emb   = (const float*)d_in[3];
    const float* W_ih  = (const float*)d_in[4];
    const float* W_hh  = (const float*)d_in[5];
    const float* b_ih  = (const float*)d_in[6];
    const float* b_hh  = (const float*)d_in[7];
    const float* W_dec = (const float*)d_in[8];
    const float* b_dec = (const float*)d_in[9];
    float* out = (float*)d_out;

    // workspace carve  (xg eliminated — input GEMM fused into lstm_persistent)
    float*          ws      = (float*)d_ws;
    float*          sumexp  = ws;                               // 8192 f32
    float*          picked  = sumexp + BT;                      // 8192 f32
    float*          bdp     = picked + BT;                      // 16384 f32 padded bias
    unsigned short* inp_bf  = (unsigned short*)(bdp + NVP);     // 8192*384  bf16
    unsigned short* hs_bf   = inp_bf + (size_t)BT * ECK;        // 8192*512  bf16
    unsigned short* wdec_bf = hs_bf + (size_t)BT * NH;          // 16384*512 bf16 (padded)
    unsigned short* whh_bf  = wdec_bf + (size_t)NVP * NH;       // 2048*512  bf16
    unsigned short* wih_bf  = whh_bf + (size_t)G4 * NH;         // 2048*384  bf16
    unsigned short* hx      = wih_bf + (size_t)G4 * ECK;        // 64*128*512 bf16 (8 MB)
    unsigned int*   flags   = (unsigned int*)(hx + (size_t)NT * NB * NH);  // 64*8*32 u32

    hipMemsetAsync(hx, 0, NB * NH * sizeof(unsigned short), stream);       // hx[0] = h0 = 0
    hipMemsetAsync(flags, 0, (size_t)NT * 256 * sizeof(unsigned int), stream);
    hipMemsetAsync(sumexp, 0, BT * sizeof(float), stream);
    // zero W_dec pad rows (16000..16383)
    hipMemsetAsync(wdec_bf + (size_t)NV * NH, 0, (size_t)(NVP - NV) * NH * sizeof(unsigned short), stream);

    pad_bdec<<<(NVP + 255) / 256, 256, 0, stream>>>(b_dec, bdp);

    f32_to_bf16<<<(NV * NH / 4 + 255) / 256, 256, 0, stream>>>(W_dec, wdec_bf, NV * NH / 4);
    f32_to_bf16<<<(G4 * NH / 4 + 255) / 256, 256, 0, stream>>>(W_hh, whh_bf, G4 * NH / 4);
    f32_to_bf16<<<(G4 * ECK / 4 + 255) / 256, 256, 0, stream>>>(W_ih, wih_bf, G4 * ECK / 4);

    build_inp_bf<<<(BT * (ECK / 4) + 255) / 256, 256, 0, stream>>>(x, ctx, emb, inp_bf);

    lstm_persistent<<<256, 256, 0, stream>>>(whh_bf, wih_bf, inp_bf, b_ih, b_hh,
                                             hx, hs_bf, flags);

    decoder_mfma<<<(NVP / 128) * (BT / 128), 256, 0, stream>>>(
        hs_bf, wdec_bf, bdp, y, sumexp, picked);

    loss_kernel<<<1, 128, 0, stream>>>(picked, sumexp, out);
}